// Round 3
// baseline (237.407 us; speedup 1.0000x reference)
//
#include <hip/hip_runtime.h>

// CRF sequence labeling: B=64, S=512, H=1024, L=9
// Pipeline (2 kernels):
//   K1 logits_chunk_kernel :
//        phase A (GEMM): feats[b][s][l] = (inputs[b,s,:]·W[l,:] + b[l]) * log2e
//          - fully-coalesced global loads (16 lanes x float4 = 256B contiguous
//            per instruction), 2 rows/lane so each LDS W fragment is FMA'd twice
//          - block covers 32 consecutive rows == exactly chunk c=bid&15 of
//            batch b=bid>>4; emissions also staged to LDS femit[32][9]
//        phase B (chunk recursion, waves 0-1 only): 9 row-recursions of the
//          9x9 log2-semiring chunk transfer matrix P_c (row i = e_i ⊗ M_ts ⊗
//          ... ⊗ M_{te-1}, M_t[i][j] = trK[i][j] + emitK[t][j]; masked steps
//          contribute identity). 9-lane groups, shuffle-vector recursion.
//        Also zeroes out[0] for K3's atomic accumulation.
//   K3 final_kernel : per batch: gold path score + alpha0 ⊗ P_0 ⊗ ... ⊗ P_15;
//        atomicAdd((norm-score)*ln2/B) into out[0].
// All LSE math in base-2 domain (inputs pre-scaled by log2 e) so
// LSE = max + log2(sum 2^x) maps to raw v_exp_f32/v_log_f32.

#define BATCH 64
#define SEQ   512
#define HID   1024
#define NLAB  9
#define CHUNK 32
#define NCHUNK (SEQ / CHUNK)   // 16

__device__ __forceinline__ float exp2_fast(float x) { return __builtin_amdgcn_exp2f(x); }
__device__ __forceinline__ float log2_fast(float x) { return __builtin_amdgcn_logf(x); }

#define LOG2E 1.4426950408889634f
#define LN2   0.6931471805599453f

// ---------------------------------------------------------------------------
// K1: fused logits + chunk recursion. Grid: (B*S/32) = 1024 blocks x 256.
// GEMM phase: wave = 4 row-groups (q = lane>>4) x 16 col-lanes (p = lane&15),
// each lane does rows rowbase+{0,1} over cols { c*256 + qq*64 + p*4 }:
//   - 16 p-lanes per (c,qq,row) read 256 contiguous bytes -> coalesced float4
//   - W float4 from LDS loaded once per (label,c,qq), FMA'd against both rows
//   - Wl unpadded [9][1024]: 16 distinct 16B slots, q-groups broadcast ->
//     2-way bank alias only (free per m136)
// Recursion phase: block's 32 rows == chunk (b = bid>>4, c = bid&15).
// waves 0-1, 9-lane groups: wave0 g=0..6 -> rows 0..6, wave1 g=0..1 -> 7..8.
// ---------------------------------------------------------------------------
__global__ __launch_bounds__(256) void logits_chunk_kernel(
    const float* __restrict__ inp, const float* __restrict__ Wg,
    const float* __restrict__ bias, const float* __restrict__ trans,
    const int* __restrict__ mask, float* __restrict__ feats,
    float* __restrict__ P, float* __restrict__ out)
{
    if (blockIdx.x == 0 && threadIdx.x == 0) out[0] = 0.0f;  // for K3's atomics

    __shared__ float Wl[NLAB * HID];        // 36 KB
    __shared__ float femit[CHUNK][NLAB];    // 1.125 KB: this block's emissions
    const int tid = threadIdx.x;
    for (int s = tid; s < NLAB * HID; s += 256)
        Wl[s] = Wg[s];
    __syncthreads();

    const int lane = tid & 63;
    const int wv   = tid >> 6;
    const int p    = lane & 15;      // column-group position
    const int q    = lane >> 4;      // row-group within wave
    const int lrow = wv * 8 + q * 2; // local row (0..31), this lane does lrow, lrow+1
    const long rowbase = (long)blockIdx.x * 32 + lrow;

    const float* r0 = inp + rowbase * HID;
    const float* r1 = r0 + HID;

    float acc0[NLAB], acc1[NLAB];
    #pragma unroll
    for (int l = 0; l < NLAB; ++l) { acc0[l] = 0.f; acc1[l] = 0.f; }

    #pragma unroll
    for (int c = 0; c < 4; ++c) {
        const int colp = c * 256 + p * 4;
        float xs0[16], xs1[16];
        #pragma unroll
        for (int qq = 0; qq < 4; ++qq) {
            ((float4*)xs0)[qq] = *(const float4*)(r0 + colp + qq * 64);
            ((float4*)xs1)[qq] = *(const float4*)(r1 + colp + qq * 64);
        }
        #pragma unroll
        for (int l = 0; l < NLAB; ++l) {
            const float* wl = &Wl[l * HID + colp];
            float a0 = acc0[l], a1 = acc1[l];
            #pragma unroll
            for (int qq = 0; qq < 4; ++qq) {
                float4 w4 = *(const float4*)(wl + qq * 64);
                float ww[4] = {w4.x, w4.y, w4.z, w4.w};
                #pragma unroll
                for (int k = 0; k < 4; ++k) {
                    a0 = fmaf(xs0[qq * 4 + k], ww[k], a0);
                    a1 = fmaf(xs1[qq * 4 + k], ww[k], a1);
                }
            }
            acc0[l] = a0; acc1[l] = a1;
        }
    }

    // reduce across the 16-lane group (xor masks 1,2,4,8 stay within group)
    #pragma unroll
    for (int l = 0; l < NLAB; ++l) {
        float a0 = acc0[l], a1 = acc1[l];
        a0 += __shfl_xor(a0, 8, 64);  a1 += __shfl_xor(a1, 8, 64);
        a0 += __shfl_xor(a0, 4, 64);  a1 += __shfl_xor(a1, 4, 64);
        a0 += __shfl_xor(a0, 2, 64);  a1 += __shfl_xor(a1, 2, 64);
        a0 += __shfl_xor(a0, 1, 64);  a1 += __shfl_xor(a1, 1, 64);
        acc0[l] = a0; acc1[l] = a1;
    }
    if (p == 0) {
        float* o0 = feats + rowbase * NLAB;
        float* o1 = o0 + NLAB;
        #pragma unroll
        for (int l = 0; l < NLAB; ++l) {
            float f0 = (acc0[l] + bias[l]) * LOG2E;
            float f1 = (acc1[l] + bias[l]) * LOG2E;
            o0[l] = f0;  femit[lrow][l]     = f0;
            o1[l] = f1;  femit[lrow + 1][l] = f1;
        }
    }
    __syncthreads();

    // ---- phase B: chunk recursion (waves 0-1) ----
    if (wv >= 2) return;

    const int c  = blockIdx.x & (NCHUNK - 1);
    const int b  = blockIdx.x >> 4;

    int g = lane / 9;                // group within wave (wave0:0..7, junk ok)
    const int jj = lane - g * 9;     // 0..8 always
    bool act = (wv == 0) ? (g < 7) : (g < 2);
    int i = act ? (wv * 7 + g) : 0;  // P-row 0..8
    const int sbase = g * 9;

    float tr[NLAB];
    #pragma unroll
    for (int k = 0; k < NLAB; ++k) tr[k] = trans[k * NLAB + jj] * LOG2E;
    const float tri = trans[i * NLAB + jj] * LOG2E;

    const int* mb = mask + b * SEQ + c * CHUNK;   // local mask base
    const int ts = (c == 0) ? 1 : 0;              // local start step

    float a;
    {
        int m0 = mb[ts];
        float e0 = femit[ts][jj];
        float aid = (i == jj) ? 0.0f : -1e30f;
        a = (m0 > 0) ? (tri + e0) : aid;
    }

    int m_nxt = mb[ts + 1];
    for (int t = ts + 1; t < CHUNK; ++t) {
        float e = femit[t][jj];
        int  mt = m_nxt;
        if (t + 1 < CHUNK) m_nxt = mb[t + 1];     // prefetch next step's mask
        float v[NLAB];
        #pragma unroll
        for (int k = 0; k < NLAB; ++k) v[k] = __shfl(a, sbase + k, 64) + tr[k];
        float m01 = fmaxf(v[0], v[1]), m23 = fmaxf(v[2], v[3]);
        float m45 = fmaxf(v[4], v[5]), m67 = fmaxf(v[6], v[7]);
        float mx = fmaxf(fmaxf(fmaxf(m01, m23), fmaxf(m45, m67)), v[8]);
        float s = 0.0f;
        #pragma unroll
        for (int k = 0; k < NLAB; ++k) s += exp2_fast(v[k] - mx);
        float an = mx + log2_fast(s) + e;
        a = (mt > 0) ? an : a;
    }
    if (act)
        P[(long)(b * NCHUNK + c) * 81 + i * NLAB + jj] = a;
}

// ---------------------------------------------------------------------------
// K3: per-batch finalize. Grid: 64 blocks x 64.
//  - gold path score (all 64 lanes, strided over t, then wave-reduce)
//  - alpha = alpha0 ⊗ P_0 ⊗ ... ⊗ P_15 (lanes replicate j = lane%9)
//  - atomicAdd (norm - score) * ln2/B into out[0] (zeroed by K1)
// ---------------------------------------------------------------------------
__global__ __launch_bounds__(64) void final_kernel(
    const float* __restrict__ feats, const float* __restrict__ trans,
    const float* __restrict__ startv, const float* __restrict__ endv,
    const int* __restrict__ labels, const int* __restrict__ mask,
    const float* __restrict__ P, float* __restrict__ out)
{
    const int b = blockIdx.x, lane = threadIdx.x;
    const float* fb = feats + (long)b * SEQ * NLAB;
    const int* lb = labels + b * SEQ;
    const int* mb = mask + b * SEQ;

    // ---- gold score ----
    float gsum = 0.0f; int msum = 0;
    for (int t = lane; t < SEQ; t += 64) {
        int tag = lb[t];
        int mt = mb[t];
        if (mt > 0) {
            gsum += fb[t * NLAB + tag];            // feats already *K
            msum++;
            if (t > 0) gsum += trans[lb[t - 1] * NLAB + tag] * LOG2E;
        }
    }
    #pragma unroll
    for (int off = 32; off > 0; off >>= 1) {
        gsum += __shfl_xor(gsum, off, 64);
        msum += __shfl_xor(msum, off, 64);
    }

    // ---- alpha chain over chunk matrices ----
    const int j = lane % 9;      // lanes >=9 replicate; shuffles read lanes 0..8
    float al = fb[j] + startv[j] * LOG2E;
    const float* Pb = P + (long)b * NCHUNK * 81;
    float pc[NLAB];
    #pragma unroll
    for (int i = 0; i < NLAB; ++i) pc[i] = Pb[i * NLAB + j];
    #pragma unroll
    for (int c = 0; c < NCHUNK; ++c) {
        float pn[NLAB];
        if (c < NCHUNK - 1) {
            #pragma unroll
            for (int i = 0; i < NLAB; ++i) pn[i] = Pb[(c + 1) * 81 + i * NLAB + j];
        } else {
            #pragma unroll
            for (int i = 0; i < NLAB; ++i) pn[i] = 0.0f;
        }
        float v[NLAB];
        #pragma unroll
        for (int i = 0; i < NLAB; ++i) v[i] = __shfl(al, i, 64) + pc[i];
        float m01 = fmaxf(v[0], v[1]), m23 = fmaxf(v[2], v[3]);
        float m45 = fmaxf(v[4], v[5]), m67 = fmaxf(v[6], v[7]);
        float mx = fmaxf(fmaxf(fmaxf(m01, m23), fmaxf(m45, m67)), v[8]);
        float s = 0.0f;
        #pragma unroll
        for (int i = 0; i < NLAB; ++i) s += exp2_fast(v[i] - mx);
        al = mx + log2_fast(s);
        #pragma unroll
        for (int i = 0; i < NLAB; ++i) pc[i] = pn[i];
    }
    al += endv[j] * LOG2E;

    // LSE over j (lanes 0..8 hold the distinct values)
    float v[NLAB];
    #pragma unroll
    for (int i = 0; i < NLAB; ++i) v[i] = __shfl(al, i, 64);
    float m01 = fmaxf(v[0], v[1]), m23 = fmaxf(v[2], v[3]);
    float m45 = fmaxf(v[4], v[5]), m67 = fmaxf(v[6], v[7]);
    float mx = fmaxf(fmaxf(fmaxf(m01, m23), fmaxf(m45, m67)), v[8]);
    float s = 0.0f;
    #pragma unroll
    for (int i = 0; i < NLAB; ++i) s += exp2_fast(v[i] - mx);
    float norm = mx + log2_fast(s);

    if (lane == 0) {
        int li = (msum > 0) ? (msum - 1) : 0;
        float score = gsum + startv[lb[0]] * LOG2E + endv[lb[li]] * LOG2E;
        atomicAdd(out, (norm - score) * (LN2 / (float)BATCH));
    }
}

extern "C" void kernel_launch(void* const* d_in, const int* in_sizes, int n_in,
                              void* d_out, int out_size, void* d_ws, size_t ws_size,
                              hipStream_t stream)
{
    const float* inp    = (const float*)d_in[0];
    const int*   labels = (const int*)d_in[1];
    const int*   mask   = (const int*)d_in[2];
    const float* W      = (const float*)d_in[3];
    const float* bias   = (const float*)d_in[4];
    const float* trans  = (const float*)d_in[5];
    const float* startv = (const float*)d_in[6];
    const float* endv   = (const float*)d_in[7];

    float* feats = (float*)d_ws;                    // B*S*L = 294912 floats
    float* P     = feats + BATCH * SEQ * NLAB;      // B*NCHUNK*81 = 82944 floats
    float* out   = (float*)d_out;

    hipLaunchKernelGGL(logits_chunk_kernel, dim3(BATCH * SEQ / 32), dim3(256), 0,
                       stream, inp, W, bias, trans, mask, feats, P, out);
    hipLaunchKernelGGL(final_kernel, dim3(BATCH), dim3(64), 0, stream,
                       feats, trans, startv, endv, labels, mask, P, out);
}